// Round 1
// baseline (931.442 us; speedup 1.0000x reference)
//
#include <hip/hip_runtime.h>
#include <hip/hip_bf16.h>

#define HW 9216
#define CDIM 256
#define NBATCH 8
#define NHEADS 8

__device__ inline float ldx(const float* p) { return *p; }
__device__ inline float ldx(const __hip_bfloat16* p) { return __bfloat162float(*p); }
__device__ inline void stx(float* p, float v) { *p = v; }
__device__ inline void stx(__hip_bfloat16* p, float v) { *p = __float2bfloat16(v); }

// ---------------- Kernel A: fuse W_cat @ [W_qr; W_qd] ----------------
__global__ void fuse_wq(const float* __restrict__ W_cat, const float* __restrict__ W_qr,
                        const float* __restrict__ W_qd, const float* __restrict__ b_qr,
                        const float* __restrict__ b_qd, const float* __restrict__ b_cat,
                        float* __restrict__ Wqx, float* __restrict__ Wqy,
                        float* __restrict__ bq) {
    int o = blockIdx.x;
    int c = threadIdx.x;
    float ax = 0.f, ay = 0.f;
    for (int i = 0; i < 128; ++i) {
        ax += W_cat[o * 256 + i] * W_qr[i * 256 + c];
        ay += W_cat[o * 256 + 128 + i] * W_qd[i * 256 + c];
    }
    Wqx[o * 256 + c] = ax;
    Wqy[o * 256 + c] = ay;
    if (c == 0) {
        float s = b_cat[o];
        for (int i = 0; i < 128; ++i)
            s += W_cat[o * 256 + i] * b_qr[i] + W_cat[o * 256 + 128 + i] * b_qd[i];
        bq[o] = s;
    }
}

// ---------------- Big conv1x1 GEMM ----------------
// Out[b,m,n] = sum_k W0[m,k]*X0[b,k,n] (+ sum_k W1[m,k]*X1[b,k,n]) + bias[m] (+resid[b,m,n])
// M=256, N=9216 per batch, K=256 per input. Tile 64x64, BK=16, 16x16 threads, 4x4 microtile.
template <typename TX, typename TOut>
__global__ __launch_bounds__(256) void gemm1x1(
    const float* __restrict__ W0, const TX* __restrict__ X0,
    const float* __restrict__ W1, const TX* __restrict__ X1,
    const float* __restrict__ bias, const float* __restrict__ resid,
    TOut* __restrict__ Out, int wbs) {
    const int b = blockIdx.z;
    const int n0 = blockIdx.x * 64;
    const int m0 = blockIdx.y * 64;
    const int tx = threadIdx.x, ty = threadIdx.y;
    const int tid = ty * 16 + tx;

    __shared__ float As[16][68];      // [k][m], stride 68 -> conflict-free, 16B-aligned rows
    __shared__ float Bs[16][64];      // [k][n]

    const float* Wb0 = W0 + (size_t)b * wbs;
    const TX* Xb0 = X0 + (size_t)b * CDIM * HW;
    const TX* Xb1 = X1 ? X1 + (size_t)b * CDIM * HW : nullptr;

    float acc[4][4] = {};
    const int nkt = W1 ? 32 : 16;

    for (int kt = 0; kt < nkt; ++kt) {
        int k0 = kt * 16;
        const float* Wp;
        const TX* Xp;
        if (k0 < 256) { Wp = Wb0; Xp = Xb0; }
        else { Wp = W1; Xp = Xb1; k0 -= 256; }

#pragma unroll
        for (int i = 0; i < 4; ++i) {
            int idx = i * 256 + tid;
            int row = idx >> 4, col = idx & 15;
            As[col][row] = Wp[(size_t)(m0 + row) * 256 + k0 + col];
        }
#pragma unroll
        for (int i = 0; i < 4; ++i) {
            int idx = i * 256 + tid;
            int r = idx >> 6, c = idx & 63;
            Bs[r][c] = ldx(&Xp[(size_t)(k0 + r) * HW + n0 + c]);
        }
        __syncthreads();

#pragma unroll
        for (int kk = 0; kk < 16; ++kk) {
            float4 a4 = *(const float4*)&As[kk][ty * 4];
            float4 b4 = *(const float4*)&Bs[kk][tx * 4];
            float av[4] = {a4.x, a4.y, a4.z, a4.w};
            float bv[4] = {b4.x, b4.y, b4.z, b4.w};
#pragma unroll
            for (int i = 0; i < 4; ++i)
#pragma unroll
                for (int j = 0; j < 4; ++j) acc[i][j] += av[i] * bv[j];
        }
        __syncthreads();
    }

#pragma unroll
    for (int i = 0; i < 4; ++i) {
        int m = m0 + ty * 4 + i;
        float bv = bias[m];
#pragma unroll
        for (int j = 0; j < 4; ++j) {
            int n = n0 + tx * 4 + j;
            size_t off = ((size_t)b * CDIM + m) * HW + n;
            float v = acc[i][j] + bv;
            if (resid) v += resid[off];
            stx(&Out[off], v);
        }
    }
}

// ---------------- Gram + sum-of-squares (per b,h; chunked over n, atomic accumulate) ----
__global__ __launch_bounds__(256) void gram_kernel(
    const __hip_bfloat16* __restrict__ q, const __hip_bfloat16* __restrict__ k,
    float* __restrict__ G, float* __restrict__ sqq, float* __restrict__ sqk) {
    const int nc = blockIdx.x;   // 72 chunks of 128
    const int h = blockIdx.y, b = blockIdx.z;
    const int t = threadIdx.x;

    __shared__ float qs[32][128];
    __shared__ float ks[32][129];  // padded: d varies across lanes

    size_t base = ((size_t)b * CDIM + h * 32) * HW + nc * 128;
#pragma unroll
    for (int i = 0; i < 16; ++i) {
        int idx = i * 256 + t;
        int row = idx >> 7, col = idx & 127;
        qs[row][col] = __bfloat162float(q[base + (size_t)row * HW + col]);
        ks[row][col] = __bfloat162float(k[base + (size_t)row * HW + col]);
    }
    __syncthreads();

    const int d = t & 31;
    const int cb = t >> 5;  // 0..7
    float acc[4] = {0.f, 0.f, 0.f, 0.f};
    for (int n = 0; n < 128; ++n) {
        float kv = ks[d][n];
#pragma unroll
        for (int p = 0; p < 4; ++p) acc[p] += qs[cb + 8 * p][n] * kv;
    }

    float* Gp = G + (size_t)(b * 8 + h) * 32 * 32;
#pragma unroll
    for (int p = 0; p < 4; ++p) atomicAdd(&Gp[(cb + 8 * p) * 32 + d], acc[p]);

    if (t < 64) {
        int c = t & 31;
        float sq = 0.f;
        if (t < 32) {
            for (int n = 0; n < 128; ++n) { float v = qs[c][n]; sq += v * v; }
            atomicAdd(&sqq[(b * 8 + h) * 32 + c], sq);
        } else {
            for (int n = 0; n < 128; ++n) { float v = ks[c][n]; sq += v * v; }
            atomicAdd(&sqk[(b * 8 + h) * 32 + c], sq);
        }
    }
}

// ---------------- normalize + temperature + softmax ----------------
__global__ __launch_bounds__(1024) void softmax_kernel(
    const float* __restrict__ G, const float* __restrict__ sqq,
    const float* __restrict__ sqk, const float* __restrict__ temp,
    float* __restrict__ A) {
    int bh = blockIdx.x;  // 64
    int h = bh & 7;
    int c = threadIdx.y, d = threadIdx.x;
    float nq = fmaxf(sqrtf(sqq[bh * 32 + c]), 1e-12f);
    float nk = fmaxf(sqrtf(sqk[bh * 32 + d]), 1e-12f);
    float v = G[(size_t)(bh * 32 + c) * 32 + d] / (nq * nk) * temp[h];
    float m = v;
    for (int s = 16; s > 0; s >>= 1) m = fmaxf(m, __shfl_xor(m, s, 32));
    float e = __expf(v - m);
    float sum = e;
    for (int s = 16; s > 0; s >>= 1) sum += __shfl_xor(sum, s, 32);
    A[(size_t)(bh * 32 + c) * 32 + d] = e / sum;
}

// ---------------- M_b[o, h*32+d] = sum_c W_proj[o, h*32+c] * A[b,h,c,d] ----------------
__global__ __launch_bounds__(256) void build_m(const float* __restrict__ W_proj,
                                               const float* __restrict__ A,
                                               float* __restrict__ M) {
    int o = blockIdx.x;  // 256
    int b = blockIdx.y;  // 8
    int t = threadIdx.x; // h*32+d
    int h = t >> 5, d = t & 31;
    const float* Ab = A + (size_t)(b * 8 + h) * 32 * 32;
    float acc = 0.f;
    for (int c = 0; c < 32; ++c)
        acc += W_proj[o * 256 + h * 32 + c] * Ab[c * 32 + d];
    M[((size_t)b * 256 + o) * 256 + t] = acc;
}

extern "C" void kernel_launch(void* const* d_in, const int* in_sizes, int n_in,
                              void* d_out, int out_size, void* d_ws, size_t ws_size,
                              hipStream_t stream) {
    const float* x = (const float*)d_in[0];
    const float* y = (const float*)d_in[1];
    const float* z = (const float*)d_in[2];
    const float* W_qr = (const float*)d_in[3];
    const float* b_qr = (const float*)d_in[4];
    const float* W_qd = (const float*)d_in[5];
    const float* b_qd = (const float*)d_in[6];
    const float* W_kf = (const float*)d_in[7];
    const float* b_kf = (const float*)d_in[8];
    const float* W_vf = (const float*)d_in[9];
    const float* b_vf = (const float*)d_in[10];
    const float* W_cat = (const float*)d_in[11];
    const float* b_cat = (const float*)d_in[12];
    const float* W_proj = (const float*)d_in[13];
    const float* b_proj = (const float*)d_in[14];
    const float* temp = (const float*)d_in[15];
    float* out = (float*)d_out;

    char* ws = (char*)d_ws;
    const size_t QKV = (size_t)NBATCH * CDIM * HW * sizeof(__hip_bfloat16);  // 37748736
    __hip_bfloat16* qb = (__hip_bfloat16*)(ws);
    __hip_bfloat16* kb = (__hip_bfloat16*)(ws + QKV);
    __hip_bfloat16* vb = (__hip_bfloat16*)(ws + 2 * QKV);
    char* p = ws + 3 * QKV;
    float* Wqx = (float*)p;            p += 256 * 256 * 4;
    float* Wqy = (float*)p;            p += 256 * 256 * 4;
    float* bq  = (float*)p;            p += 1024;
    float* G   = (float*)p;            p += 64 * 32 * 32 * 4;   // 262144
    float* sqq = (float*)p;            p += 2048 * 4;
    float* sqk = (float*)p;            p += 2048 * 4;
    float* A   = (float*)p;            p += 64 * 32 * 32 * 4;
    float* M   = (float*)p;            p += (size_t)8 * 256 * 256 * 4;

    // zero the atomic accumulators (G, sqq, sqk are contiguous)
    hipMemsetAsync(G, 0, 262144 + 8192 + 8192, stream);

    fuse_wq<<<256, 256, 0, stream>>>(W_cat, W_qr, W_qd, b_qr, b_qd, b_cat, Wqx, Wqy, bq);

    dim3 gg(HW / 64, CDIM / 64, NBATCH);
    dim3 gb(16, 16);
    gemm1x1<float, __hip_bfloat16><<<gg, gb, 0, stream>>>(Wqx, x, Wqy, y, bq, nullptr, qb, 0);
    gemm1x1<float, __hip_bfloat16><<<gg, gb, 0, stream>>>(W_kf, z, nullptr, nullptr, b_kf, nullptr, kb, 0);
    gemm1x1<float, __hip_bfloat16><<<gg, gb, 0, stream>>>(W_vf, z, nullptr, nullptr, b_vf, nullptr, vb, 0);

    gram_kernel<<<dim3(HW / 128, NHEADS, NBATCH), 256, 0, stream>>>(qb, kb, G, sqq, sqk);
    softmax_kernel<<<64, dim3(32, 32), 0, stream>>>(G, sqq, sqk, temp, A);
    build_m<<<dim3(256, 8), 256, 0, stream>>>(W_proj, A, M);

    gemm1x1<__hip_bfloat16, float><<<gg, gb, 0, stream>>>(M, vb, nullptr, nullptr, b_proj, z, out, 256 * 256);
}

// Round 2
// 521.544 us; speedup vs baseline: 1.7859x; 1.7859x over previous
//
#include <hip/hip_runtime.h>
#include <hip/hip_bf16.h>

#define HW 9216
#define CDIM 256
#define NBATCH 8
#define NHEADS 8

typedef __bf16 bf16x8 __attribute__((ext_vector_type(8)));
typedef float f32x4 __attribute__((ext_vector_type(4)));

__device__ inline unsigned short f2bf(float f) {
    unsigned int u = __builtin_bit_cast(unsigned int, f);
    u = (u + 0x7FFF + ((u >> 16) & 1)) >> 16;
    return (unsigned short)u;
}
__device__ inline float bf2f(unsigned short s) {
    unsigned int u = ((unsigned int)s) << 16;
    return __builtin_bit_cast(float, u);
}
__device__ inline unsigned int pk2(float a, float b) {
    return (unsigned int)f2bf(a) | ((unsigned int)f2bf(b) << 16);
}
__device__ inline float ldx(const float* p) { return *p; }
__device__ inline float ldx(const unsigned short* p) { return bf2f(*p); }
__device__ inline void stx(float* p, float v) { *p = v; }
__device__ inline void stx(unsigned short* p, float v) { *p = f2bf(v); }

// ---------------- fuse W_cat @ [W_qr; W_qd] -> bf16 Wq [256][512], fp32 bq ----------------
__global__ void fuse_wq(const float* __restrict__ W_cat, const float* __restrict__ W_qr,
                        const float* __restrict__ W_qd, const float* __restrict__ b_qr,
                        const float* __restrict__ b_qd, const float* __restrict__ b_cat,
                        unsigned short* __restrict__ Wq, float* __restrict__ bq) {
    int o = blockIdx.x;
    int c = threadIdx.x;
    float ax = 0.f, ay = 0.f;
    for (int i = 0; i < 128; ++i) {
        ax += W_cat[o * 256 + i] * W_qr[i * 256 + c];
        ay += W_cat[o * 256 + 128 + i] * W_qd[i * 256 + c];
    }
    Wq[o * 512 + c] = f2bf(ax);
    Wq[o * 512 + 256 + c] = f2bf(ay);
    if (c == 0) {
        float s = b_cat[o];
        for (int i = 0; i < 128; ++i)
            s += W_cat[o * 256 + i] * b_qr[i] + W_cat[o * 256 + 128 + i] * b_qd[i];
        bq[o] = s;
    }
}

// ---------------- convert W_kf, W_vf to bf16 ----------------
__global__ void cvt_w(const float* __restrict__ a, const float* __restrict__ b,
                      unsigned short* __restrict__ oa, unsigned short* __restrict__ ob) {
    int i = blockIdx.x * 256 + threadIdx.x;  // 65536 elements each
    oa[i] = f2bf(a[i]);
    ob[i] = f2bf(b[i]);
}

// ---------------- MFMA conv1x1 GEMM ----------------
// Out[b,m,n] = sum_k A[m,k]*X[b,k,n] + bias[m] (+resid). A bf16 [256][Ktot] (batch stride a_bs).
// X = X0 for k<256, X1 for k>=256 (q-GEMM K=512). Block tile 128x128, 4 waves of 64x64, BK=32.
template <typename TX, typename TOut>
__global__ __launch_bounds__(256) void gemm_mfma(
    const unsigned short* __restrict__ A, int a_bs, int Ktot,
    const TX* __restrict__ X0, const TX* __restrict__ X1,
    const float* __restrict__ bias, const float* __restrict__ resid,
    TOut* __restrict__ Out) {
    const int b = blockIdx.z;
    const int n0 = blockIdx.x * 128;
    const int m0 = blockIdx.y * 128;
    const int tid = threadIdx.x;
    const int lane = tid & 63;
    const int wid = tid >> 6;
    const int wm = (wid >> 1) * 64;
    const int wn = (wid & 1) * 64;
    const int l15 = lane & 15;
    const int quad = lane >> 4;

    // B tile staged in A/B-fragment order: [kquad(4)][n(128)][j(8)] bf16 = 8 KB
    __shared__ __align__(16) unsigned short Bs[4 * 128 * 8];

    const unsigned short* Ab = A + (size_t)b * a_bs;
    const TX* Xb0 = X0 + (size_t)b * CDIM * HW;
    const TX* Xb1 = X1 ? X1 + (size_t)b * CDIM * HW : nullptr;

    f32x4 acc[4][4] = {};

    const int sn = tid & 127;           // staged n within tile
    const int sq0 = (tid >> 7) * 2;     // staged kquad pair

    for (int k0 = 0; k0 < Ktot; k0 += 32) {
        const TX* Xp = (k0 < 256) ? Xb0 : Xb1;
        const int k0r = k0 & 255;

        // ---- stage B: each thread owns 2 (kquad,n) cells of 8 k-values ----
#pragma unroll
        for (int qq = 0; qq < 2; ++qq) {
            int q = sq0 + qq;
            const TX* src = Xp + (size_t)(k0r + q * 8) * HW + n0 + sn;
            float f[8];
#pragma unroll
            for (int j = 0; j < 8; ++j) f[j] = ldx(src + (size_t)j * HW);
            uint4 pk;
            pk.x = pk2(f[0], f[1]);
            pk.y = pk2(f[2], f[3]);
            pk.z = pk2(f[4], f[5]);
            pk.w = pk2(f[6], f[7]);
            *(uint4*)&Bs[(q * 128 + sn) * 8] = pk;  // contiguous 16B ds_write_b128
        }

        // ---- A fragments straight from global (L2-hot weights) ----
        bf16x8 af[4];
#pragma unroll
        for (int mi = 0; mi < 4; ++mi)
            af[mi] = *(const bf16x8*)(Ab + (size_t)(m0 + wm + mi * 16 + l15) * Ktot + k0 + quad * 8);

        __syncthreads();

        bf16x8 bfr[4];
#pragma unroll
        for (int nj = 0; nj < 4; ++nj)
            bfr[nj] = *(const bf16x8*)&Bs[(quad * 128 + wn + nj * 16 + l15) * 8];

#pragma unroll
        for (int mi = 0; mi < 4; ++mi)
#pragma unroll
            for (int nj = 0; nj < 4; ++nj)
                acc[mi][nj] = __builtin_amdgcn_mfma_f32_16x16x32_bf16(af[mi], bfr[nj], acc[mi][nj], 0, 0, 0);

        __syncthreads();
    }

    // ---- epilogue: C/D layout col(n)=lane&15, row(m)=quad*4+reg ----
#pragma unroll
    for (int mi = 0; mi < 4; ++mi) {
#pragma unroll
        for (int r = 0; r < 4; ++r) {
            int m = m0 + wm + mi * 16 + quad * 4 + r;
            float bv = bias[m];
#pragma unroll
            for (int nj = 0; nj < 4; ++nj) {
                int n = n0 + wn + nj * 16 + l15;
                size_t off = ((size_t)b * CDIM + m) * HW + n;
                float v = acc[mi][nj][r] + bv;
                if (resid) v += resid[off];
                stx(&Out[off], v);
            }
        }
    }
}

// ---------------- Gram + sum-of-squares (per b,h; chunked over n, atomic accumulate) ----
__global__ __launch_bounds__(256) void gram_kernel(
    const unsigned short* __restrict__ q, const unsigned short* __restrict__ k,
    float* __restrict__ G, float* __restrict__ sqq, float* __restrict__ sqk) {
    const int nc = blockIdx.x;   // 72 chunks of 128
    const int h = blockIdx.y, b = blockIdx.z;
    const int t = threadIdx.x;

    __shared__ float qs[32][128];
    __shared__ float ks[32][129];

    size_t base = ((size_t)b * CDIM + h * 32) * HW + nc * 128;
#pragma unroll
    for (int i = 0; i < 16; ++i) {
        int idx = i * 256 + t;
        int row = idx >> 7, col = idx & 127;
        qs[row][col] = bf2f(q[base + (size_t)row * HW + col]);
        ks[row][col] = bf2f(k[base + (size_t)row * HW + col]);
    }
    __syncthreads();

    const int d = t & 31;
    const int cb = t >> 5;
    float acc[4] = {0.f, 0.f, 0.f, 0.f};
    for (int n = 0; n < 128; ++n) {
        float kv = ks[d][n];
#pragma unroll
        for (int p = 0; p < 4; ++p) acc[p] += qs[cb + 8 * p][n] * kv;
    }

    float* Gp = G + (size_t)(b * 8 + h) * 32 * 32;
#pragma unroll
    for (int p = 0; p < 4; ++p) atomicAdd(&Gp[(cb + 8 * p) * 32 + d], acc[p]);

    if (t < 64) {
        int c = t & 31;
        float sq = 0.f;
        if (t < 32) {
            for (int n = 0; n < 128; ++n) { float v = qs[c][n]; sq += v * v; }
            atomicAdd(&sqq[(b * 8 + h) * 32 + c], sq);
        } else {
            for (int n = 0; n < 128; ++n) { float v = ks[c][n]; sq += v * v; }
            atomicAdd(&sqk[(b * 8 + h) * 32 + c], sq);
        }
    }
}

// ---------------- normalize + temperature + softmax ----------------
__global__ __launch_bounds__(1024) void softmax_kernel(
    const float* __restrict__ G, const float* __restrict__ sqq,
    const float* __restrict__ sqk, const float* __restrict__ temp,
    float* __restrict__ A) {
    int bh = blockIdx.x;
    int h = bh & 7;
    int c = threadIdx.y, d = threadIdx.x;
    float nq = fmaxf(sqrtf(sqq[bh * 32 + c]), 1e-12f);
    float nk = fmaxf(sqrtf(sqk[bh * 32 + d]), 1e-12f);
    float v = G[(size_t)(bh * 32 + c) * 32 + d] / (nq * nk) * temp[h];
    float m = v;
    for (int s = 16; s > 0; s >>= 1) m = fmaxf(m, __shfl_xor(m, s, 32));
    float e = __expf(v - m);
    float sum = e;
    for (int s = 16; s > 0; s >>= 1) sum += __shfl_xor(sum, s, 32);
    A[(size_t)(bh * 32 + c) * 32 + d] = e / sum;
}

// ---------------- M_b[o, h*32+d] = sum_c W_proj[o, h*32+c] * A[b,h,c,d] -> bf16 ----------------
__global__ __launch_bounds__(256) void build_m(const float* __restrict__ W_proj,
                                               const float* __restrict__ A,
                                               unsigned short* __restrict__ M) {
    int o = blockIdx.x;
    int b = blockIdx.y;
    int t = threadIdx.x;
    int h = t >> 5, d = t & 31;
    const float* Ab = A + (size_t)(b * 8 + h) * 32 * 32;
    float acc = 0.f;
    for (int c = 0; c < 32; ++c)
        acc += W_proj[o * 256 + h * 32 + c] * Ab[c * 32 + d];
    M[((size_t)b * 256 + o) * 256 + t] = f2bf(acc);
}

extern "C" void kernel_launch(void* const* d_in, const int* in_sizes, int n_in,
                              void* d_out, int out_size, void* d_ws, size_t ws_size,
                              hipStream_t stream) {
    const float* x = (const float*)d_in[0];
    const float* y = (const float*)d_in[1];
    const float* z = (const float*)d_in[2];
    const float* W_qr = (const float*)d_in[3];
    const float* b_qr = (const float*)d_in[4];
    const float* W_qd = (const float*)d_in[5];
    const float* b_qd = (const float*)d_in[6];
    const float* W_kf = (const float*)d_in[7];
    const float* b_kf = (const float*)d_in[8];
    const float* W_vf = (const float*)d_in[9];
    const float* b_vf = (const float*)d_in[10];
    const float* W_cat = (const float*)d_in[11];
    const float* b_cat = (const float*)d_in[12];
    const float* W_proj = (const float*)d_in[13];
    const float* b_proj = (const float*)d_in[14];
    const float* temp = (const float*)d_in[15];
    float* out = (float*)d_out;

    char* ws = (char*)d_ws;
    const size_t NT = (size_t)NBATCH * CDIM * HW;  // elements per tensor
    unsigned short* qb = (unsigned short*)ws;
    unsigned short* kb = qb + NT;
    unsigned short* vb = kb + NT;
    char* p = (char*)(vb + NT);
    unsigned short* Wq = (unsigned short*)p;  p += 256 * 512 * 2;
    unsigned short* Wk = (unsigned short*)p;  p += 256 * 256 * 2;
    unsigned short* Wv = (unsigned short*)p;  p += 256 * 256 * 2;
    float* bq  = (float*)p;                   p += 1024;
    float* G   = (float*)p;                   p += 64 * 32 * 32 * 4;
    float* sqq = (float*)p;                   p += 2048 * 4;
    float* sqk = (float*)p;                   p += 2048 * 4;
    float* Aat = (float*)p;                   p += 64 * 32 * 32 * 4;
    unsigned short* Mb = (unsigned short*)p;  p += (size_t)8 * 256 * 256 * 2;

    hipMemsetAsync(G, 0, 262144 + 8192 + 8192, stream);

    fuse_wq<<<256, 256, 0, stream>>>(W_cat, W_qr, W_qd, b_qr, b_qd, b_cat, Wq, bq);
    cvt_w<<<256, 256, 0, stream>>>(W_kf, W_vf, Wk, Wv);

    dim3 gg(HW / 128, CDIM / 128, NBATCH);
    gemm_mfma<float, unsigned short><<<gg, 256, 0, stream>>>(Wq, 0, 512, x, y, bq, nullptr, qb);
    gemm_mfma<float, unsigned short><<<gg, 256, 0, stream>>>(Wk, 0, 256, z, nullptr, b_kf, nullptr, kb);
    gemm_mfma<float, unsigned short><<<gg, 256, 0, stream>>>(Wv, 0, 256, z, nullptr, b_vf, nullptr, vb);

    gram_kernel<<<dim3(HW / 128, NHEADS, NBATCH), 256, 0, stream>>>(qb, kb, G, sqq, sqk);
    softmax_kernel<<<64, dim3(32, 32), 0, stream>>>(G, sqq, sqk, temp, Aat);
    build_m<<<dim3(256, 8), 256, 0, stream>>>(W_proj, Aat, Mb);

    gemm_mfma<unsigned short, float><<<gg, 256, 0, stream>>>(Mb, 256 * 256, 256, vb, nullptr, b_proj, z, out);
}